// Round 6
// baseline (337.639 us; speedup 1.0000x reference)
//
#include <hip/hip_runtime.h>
#include <math.h>

#define VOCAB 4096
#define EMBED 64
#define OBSD  128
#define HIDD  512
#define BNR   4096        // batch rows (1024*4)
#define ZR    65536       // token rows (BNR*16)
#define ZD    1024        // 16*EMBED
#define NCHUNK 4
#define CHSZ  (VOCAB / NCHUNK)   // 1024 codes per chunk
#define TCODES 64                // codes per LDS tile
#define NTILES (CHSZ / TCODES)   // 16 tiles per chunk

// scaled units: codebook scaled by 4096 in f16 space; margin covers worst-case
// f16-split + fp32-accum error (~5e-5) with 40x slack. Proven r1/r2/r4/r5.
#define MARGIN_SCALED 2.0e-3f

// LDS layout strides (halfs), padded: slice stride 136 (not 128) to break
// power-of-2 bank alignment between k-slices.
#define SSTR 136
#define GSTR (8 * SSTR)          // 1088 halfs per 16-code group
#define TYPSZ (4 * GSTR)         // 4352 halfs per {hi|lo} per buffer

typedef _Float16 half8  __attribute__((ext_vector_type(8)));
typedef short    bf16x8 __attribute__((ext_vector_type(8)));
typedef float    f32x4  __attribute__((ext_vector_type(4)));

__device__ __forceinline__ f32x4 mfma_f16(half8 a, half8 b, f32x4 c){
  return __builtin_amdgcn_mfma_f32_16x16x32_f16(a,b,c,0,0,0);
}
__device__ __forceinline__ f32x4 mfma_bf(bf16x8 a, bf16x8 b, f32x4 c){
  return __builtin_amdgcn_mfma_f32_16x16x32_bf16(a,b,c,0,0,0);
}
__device__ __forceinline__ unsigned short f2bf(float f){
  union{float f; unsigned u;} x; x.f=f;
  unsigned u = x.u + 0x7fffu + ((x.u>>16)&1u);
  return (unsigned short)(u>>16);
}
__device__ __forceinline__ float bf2f(unsigned short h){
  union{unsigned u; float f;} x; x.u = ((unsigned)h)<<16; return x.f;
}
__device__ __forceinline__ void split3(float w, unsigned short& b1,
                                       unsigned short& b2, unsigned short& b3){
  b1 = f2bf(w); float r  = w - bf2f(b1);
  b2 = f2bf(r); float r2 = r - bf2f(b2);
  b3 = f2bf(r2);
}
__device__ __forceinline__ bf16x8 ldbf(const unsigned short* p){
  return *(const bf16x8*)(const void*)p;
}

// ---------- fused prep: cb f16-split + weight splits/transposes + rcnt zero
__global__ __launch_bounds__(256) void prep_all_kernel(
    const float* __restrict__ cb, _Float16* __restrict__ chi,
    _Float16* __restrict__ clo, float* __restrict__ bcol,
    const float* __restrict__ ew1, unsigned short* __restrict__ w1t1,
    unsigned short* __restrict__ w1t2, unsigned short* __restrict__ w1t3,
    const float* __restrict__ ew2, unsigned short* __restrict__ w2t1,
    unsigned short* __restrict__ w2t2, unsigned short* __restrict__ w2t3,
    const float* __restrict__ obs, unsigned short* __restrict__ o1,
    unsigned short* __restrict__ o2, unsigned short* __restrict__ o3,
    const float* __restrict__ dw1, unsigned short* __restrict__ d1t,
    const float* __restrict__ dw2, unsigned short* __restrict__ d2t,
    int* __restrict__ rcnt)
{
  const int b = blockIdx.x;
  const int t = threadIdx.x;
  if (b == 0 && t == 0) *rcnt = 0;
  if (b < 16) {
    // codebook: f16 hi/lo split (x4096 scale) + (-0.5*||c||^2)*4096
    int j = b * 256 + t;
    double s = 0.0;
    #pragma unroll 8
    for (int d = 0; d < EMBED; ++d) {
      float c = cb[j * EMBED + d];
      s += (double)c * (double)c;
      float cs = c * 4096.0f;             // exact (pow2 scale)
      _Float16 hi = (_Float16)cs;
      chi[j * EMBED + d] = hi;
      clo[j * EMBED + d] = (_Float16)(cs - (float)hi);
    }
    bcol[j] = (float)(-0.5 * s * 4096.0);
  } else if (b < 272) {
    // ew1 [OBSD][HIDD] -> 3-split [HIDD][OBSD]
    int e = (b - 16) * 256 + t;
    int n = e / OBSD, k = e % OBSD;
    split3(ew1[(size_t)k * HIDD + n], w1t1[e], w1t2[e], w1t3[e]);
  } else if (b < 2320) {
    // ew2 [HIDD][ZD] -> 3-split [ZD][HIDD]
    int e = (b - 272) * 256 + t;
    int n = e / HIDD, k = e % HIDD;
    split3(ew2[(size_t)k * ZD + n], w2t1[e], w2t2[e], w2t3[e]);
  } else if (b < 4368) {
    // obs elementwise 3-split
    int e = (b - 2320) * 256 + t;
    split3(obs[e], o1[e], o2[e], o3[e]);
  } else if (b < 6416) {
    // dw1 [ZD][HIDD] -> bf16 [HIDD][ZD]
    int e = (b - 4368) * 256 + t;
    int n = e / ZD, k = e % ZD;
    d1t[e] = f2bf(dw1[(size_t)k * HIDD + n]);
  } else {
    // dw2 [HIDD][OBSD] -> bf16 [OBSD][HIDD]
    int e = (b - 6416) * 256 + t;
    int n = e / HIDD, k = e % HIDD;
    d2t[e] = f2bf(dw2[(size_t)k * OBSD + n]);
  }
}

// ---------- encoder GEMM: bf16 3-split, 6 MFMA passes, per-k-step fp64 drain.
template<bool RELU>
__global__ __launch_bounds__(256) void enc_mfma_kernel(
    const unsigned short* __restrict__ A1, const unsigned short* __restrict__ A2,
    const unsigned short* __restrict__ A3,
    const unsigned short* __restrict__ B1, const unsigned short* __restrict__ B2,
    const unsigned short* __restrict__ B3,
    const float* __restrict__ bias, int M, int N, int K,
    unsigned short* __restrict__ H1, unsigned short* __restrict__ H2,
    unsigned short* __restrict__ H3,
    float* __restrict__ Z, _Float16* __restrict__ Zhi, _Float16* __restrict__ Zlo)
{
  const int tid  = threadIdx.x;
  const int wave = tid >> 6;
  const int lane = tid & 63;
  const int l15  = lane & 15;
  const int lg   = lane >> 4;
  const int m0 = blockIdx.x * 64 + (wave >> 1) * 32;
  const int n0 = blockIdx.y * 64 + (wave & 1) * 32;

  double accd[2][2][4] = {};

  for (int k0 = 0; k0 < K; k0 += 32) {
    bf16x8 a1[2], a2[2], a3[2], b1[2], b2[2], b3[2];
    #pragma unroll
    for (int ms = 0; ms < 2; ++ms) {
      size_t base = (size_t)(m0 + ms * 16 + l15) * K + k0 + lg * 8;
      a1[ms] = ldbf(A1 + base); a2[ms] = ldbf(A2 + base); a3[ms] = ldbf(A3 + base);
    }
    #pragma unroll
    for (int ns = 0; ns < 2; ++ns) {
      size_t base = (size_t)(n0 + ns * 16 + l15) * K + k0 + lg * 8;
      b1[ns] = ldbf(B1 + base); b2[ns] = ldbf(B2 + base); b3[ns] = ldbf(B3 + base);
    }
    #pragma unroll
    for (int ms = 0; ms < 2; ++ms)
      #pragma unroll
      for (int ns = 0; ns < 2; ++ns) {
        f32x4 acc = {0.f, 0.f, 0.f, 0.f};
        // smallest terms first, dominant a1*b1 last
        acc = mfma_bf(a1[ms], b3[ns], acc);
        acc = mfma_bf(a2[ms], b2[ns], acc);
        acc = mfma_bf(a3[ms], b1[ns], acc);
        acc = mfma_bf(a1[ms], b2[ns], acc);
        acc = mfma_bf(a2[ms], b1[ns], acc);
        acc = mfma_bf(a1[ms], b1[ns], acc);
        #pragma unroll
        for (int r = 0; r < 4; ++r) accd[ms][ns][r] += (double)acc[r];
      }
  }

  #pragma unroll
  for (int ms = 0; ms < 2; ++ms)
    #pragma unroll
    for (int ns = 0; ns < 2; ++ns)
      #pragma unroll
      for (int r = 0; r < 4; ++r) {
        int row = m0 + ms * 16 + lg * 4 + r;
        int col = n0 + ns * 16 + l15;
        float v = (float)accd[ms][ns][r] + bias[col];
        size_t o = (size_t)row * N + col;
        if constexpr (RELU) {
          v = v > 0.f ? v : 0.f;
          split3(v, H1[o], H2[o], H3[o]);
        } else {
          Z[o] = v;
          _Float16 hi = (_Float16)v;
          Zhi[o] = hi;
          Zlo[o] = (_Float16)(v - (float)hi);
        }
      }
}

// ---------- decoder GEMM: plain bf16 1-pass MFMA (2%-of-max tolerance)
template<bool RELU, bool OUTBF>
__global__ __launch_bounds__(256) void dec_mfma_kernel(
    const unsigned short* __restrict__ A, const unsigned short* __restrict__ B,
    const float* __restrict__ bias, int M, int N, int K,
    unsigned short* __restrict__ Obf, float* __restrict__ Of)
{
  const int tid  = threadIdx.x;
  const int wave = tid >> 6;
  const int lane = tid & 63;
  const int l15  = lane & 15;
  const int lg   = lane >> 4;
  const int m0 = blockIdx.x * 64 + (wave >> 1) * 32;
  const int n0 = blockIdx.y * 64 + (wave & 1) * 32;

  f32x4 acc[2][2] = {};
  for (int k0 = 0; k0 < K; k0 += 32) {
    bf16x8 a[2], b[2];
    #pragma unroll
    for (int ms = 0; ms < 2; ++ms)
      a[ms] = ldbf(A + (size_t)(m0 + ms * 16 + l15) * K + k0 + lg * 8);
    #pragma unroll
    for (int ns = 0; ns < 2; ++ns)
      b[ns] = ldbf(B + (size_t)(n0 + ns * 16 + l15) * K + k0 + lg * 8);
    #pragma unroll
    for (int ms = 0; ms < 2; ++ms)
      #pragma unroll
      for (int ns = 0; ns < 2; ++ns)
        acc[ms][ns] = mfma_bf(a[ms], b[ns], acc[ms][ns]);
  }
  #pragma unroll
  for (int ms = 0; ms < 2; ++ms)
    #pragma unroll
    for (int ns = 0; ns < 2; ++ns)
      #pragma unroll
      for (int r = 0; r < 4; ++r) {
        int row = m0 + ms * 16 + lg * 4 + r;
        int col = n0 + ns * 16 + l15;
        float v = acc[ms][ns][r] + bias[col];
        if constexpr (RELU) v = v > 0.f ? v : 0.f;
        if constexpr (OUTBF) Obf[(size_t)row * N + col] = f2bf(v);
        else                 Of[(size_t)row * N + col] = v;
      }
}

// ---------- VQ distance, chunked + LDS-staged codebook, 64 rows/wave.
// Block: 256 thr = 4 waves, each wave owns 64 rows (4 16-row subtiles) so the
// shared 64-code tile is re-read from LDS by 4 waves instead of 8 (r5: LDS-read
// volume was the #2 cost after the MFMA floor). Single 6-MFMA chain per
// (s,grp) seeded with bcol (kills combine adds; seed regs CSE across s).
// NOTE: no min-waves clause — a VGPR cap makes the compiler demote the
// loop-invariant z fragments to per-iteration reloads (r3: 2 GB HBM, 3x slower).
__global__ __launch_bounds__(256) void dist_kernel(
    const _Float16* __restrict__ zhi, const _Float16* __restrict__ zlo,
    const _Float16* __restrict__ chi, const _Float16* __restrict__ clo,
    const float* __restrict__ bcol,
    float2* __restrict__ pb2, int* __restrict__ pidx)
{
  __shared__ _Float16 sh[2][2][TYPSZ];   // [buf][hi|lo][padded tile]
  __shared__ float    sbc[CHSZ];

  const int tid  = threadIdx.x;
  const int wave = tid >> 6;
  const int lane = tid & 63;
  const int l15  = lane & 15;
  const int lg   = lane >> 4;
  const int rowW = blockIdx.x * 256 + wave * 64;
  const int ch   = blockIdx.y;

  // z fragments: loop-invariant, stay in VGPRs (4 subtiles x 4 frags x 4 regs)
  half8 ah0[4], ah1[4], al0[4], al1[4];
  #pragma unroll
  for (int s = 0; s < 4; ++s) {
    const size_t base = (size_t)(rowW + s * 16 + l15) * EMBED + lg * 8;
    ah0[s] = *(const half8*)(zhi + base);
    ah1[s] = *(const half8*)(zhi + base + 32);
    al0[s] = *(const half8*)(zlo + base);
    al1[s] = *(const half8*)(zlo + base + 32);
  }

  // staging: 1024 16B-chunks per tile (512 hi + 512 lo); thread t handles
  // {t, t+256} of hi and {t, t+256} of lo — each load perfectly coalesced.
  const _Float16* ghi = chi + (size_t)ch * CHSZ * EMBED;
  const _Float16* glo = clo + (size_t)ch * CHSZ * EMBED;
  // LDS dest for chunk cc (within type): code=cc>>3, slice=cc&7
  const int ccA = tid,      codeA = ccA >> 3, slA = ccA & 7;
  const int ccB = tid + 256, codeB = ccB >> 3, slB = ccB & 7;
  const int ldA = (codeA >> 4) * GSTR + slA * SSTR + (codeA & 15) * 8;
  const int ldB = (codeB >> 4) * GSTR + slB * SSTR + (codeB & 15) * 8;

  // bcol for this chunk -> LDS
  for (int i = tid; i < CHSZ; i += 256) sbc[i] = bcol[ch * CHSZ + i];

  // prologue: stage tile 0 into buf 0
  {
    *(half8*)(&sh[0][0][ldA]) = *(const half8*)(ghi + (size_t)ccA * 8);
    *(half8*)(&sh[0][0][ldB]) = *(const half8*)(ghi + (size_t)ccB * 8);
    *(half8*)(&sh[0][1][ldA]) = *(const half8*)(glo + (size_t)ccA * 8);
    *(half8*)(&sh[0][1][ldB]) = *(const half8*)(glo + (size_t)ccB * 8);
  }
  __syncthreads();

  float best[4][4], second[4][4];
  int   bidx[4][4];
  #pragma unroll
  for (int s = 0; s < 4; ++s)
    #pragma unroll
    for (int r = 0; r < 4; ++r) {
      best[s][r] = -INFINITY; second[s][r] = -INFINITY; bidx[s][r] = 0;
    }

  for (int tile = 0; tile < NTILES; ++tile) {
    const int buf = tile & 1;
    // issue next tile's global loads early; written to LDS after the barrier
    half8 v0 = {}, v1 = {}, v2 = {}, v3 = {};
    if (tile + 1 < NTILES) {
      const size_t goff = (size_t)(tile + 1) * 4096;
      v0 = *(const half8*)(ghi + goff + (size_t)ccA * 8);
      v1 = *(const half8*)(ghi + goff + (size_t)ccB * 8);
      v2 = *(const half8*)(glo + goff + (size_t)ccA * 8);
      v3 = *(const half8*)(glo + goff + (size_t)ccB * 8);
    }

    const _Float16* ph = &sh[buf][0][0];
    const _Float16* pl = &sh[buf][1][0];
    #pragma unroll
    for (int grp = 0; grp < 4; ++grp) {
      const int rb = grp * GSTR + l15 * 8;
      half8 bh0 = *(const half8*)(ph + rb + lg * SSTR);
      half8 bh1 = *(const half8*)(ph + rb + (4 + lg) * SSTR);
      half8 bl0 = *(const half8*)(pl + rb + lg * SSTR);
      half8 bl1 = *(const half8*)(pl + rb + (4 + lg) * SSTR);
      const int cloc = tile * TCODES + grp * 16 + l15;
      const int col  = ch * CHSZ + cloc;
      const float vb = sbc[cloc];
      const f32x4 seed = {vb, vb, vb, vb};     // shared across the 4 s-chains
      #pragma unroll
      for (int s = 0; s < 4; ++s) {
        // single chain, smallest terms first, dominant hi*hi last
        f32x4 acc = seed;
        acc = mfma_f16(ah0[s], bl0, acc);
        acc = mfma_f16(ah1[s], bl1, acc);
        acc = mfma_f16(al0[s], bh0, acc);
        acc = mfma_f16(al1[s], bh1, acc);
        acc = mfma_f16(ah0[s], bh0, acc);
        acc = mfma_f16(ah1[s], bh1, acc);
        #pragma unroll
        for (int r = 0; r < 4; ++r) {
          float v = acc[r];
          float sn = __builtin_amdgcn_fmed3f(second[s][r], best[s][r], v);
          bool gt = v > best[s][r];
          best[s][r] = gt ? v : best[s][r];
          bidx[s][r] = gt ? col : bidx[s][r];
          second[s][r] = sn;
        }
      }
    }
    __syncthreads();              // all waves done reading buf^1 (last iter)
    if (tile + 1 < NTILES) {
      *(half8*)(&sh[buf ^ 1][0][ldA]) = v0;
      *(half8*)(&sh[buf ^ 1][0][ldB]) = v1;
      *(half8*)(&sh[buf ^ 1][1][ldA]) = v2;
      *(half8*)(&sh[buf ^ 1][1][ldB]) = v3;
    }
    __syncthreads();              // next tile visible
  }

  // reduce (best,second,idx) across the 16 col-lanes (low 4 lane bits)
  #pragma unroll
  for (int m = 1; m <= 8; m <<= 1) {
    #pragma unroll
    for (int s = 0; s < 4; ++s)
      #pragma unroll
      for (int r = 0; r < 4; ++r) {
        float ob = __shfl_xor(best[s][r], m, 64);
        float os = __shfl_xor(second[s][r], m, 64);
        int   oi = __shfl_xor(bidx[s][r], m, 64);
        float mn = fminf(best[s][r], ob);
        second[s][r] = fmaxf(mn, fmaxf(second[s][r], os));
        if (ob > best[s][r]) { best[s][r] = ob; bidx[s][r] = oi; }
      }
  }

  if (l15 == 0) {
    #pragma unroll
    for (int s = 0; s < 4; ++s)
      #pragma unroll
      for (int r = 0; r < 4; ++r) {
        int row = rowW + s * 16 + lg * 4 + r;
        pb2 [(size_t)ch * ZR + row] = make_float2(best[s][r], second[s][r]);
        pidx[(size_t)ch * ZR + row] = bidx[s][r];
      }
  }
}

// ---------- merge chunk partials -> tokens + rescue list
__global__ __launch_bounds__(256) void merge_kernel(
    const float2* __restrict__ pb2, const int* __restrict__ pidx,
    int* __restrict__ tokens, int* __restrict__ rcnt, int* __restrict__ rrows)
{
  int r = blockIdx.x * 256 + threadIdx.x;
  float b = -INFINITY, s = -INFINITY;
  int bi = 0;
  #pragma unroll
  for (int c = 0; c < NCHUNK; ++c) {
    float2 p = pb2[(size_t)c * ZR + r];
    int    i = pidx[(size_t)c * ZR + r];
    if (p.x > b) { s = fmaxf(b, p.y); b = p.x; bi = i; }
    else         { s = fmaxf(s, p.x); }
  }
  tokens[r] = bi;
  if (b - s < MARGIN_SCALED) {
    int p = atomicAdd(rcnt, 1);
    if (p < ZR) rrows[p] = r;
  }
}

// ---------- exact fp64 rescan for ambiguous tokens (correctness anchor)
__global__ __launch_bounds__(256) void rescue_kernel(
    const int* __restrict__ cnt, const int* __restrict__ rows,
    const float* __restrict__ z, const float* __restrict__ cb,
    int* __restrict__ tokens)
{
  __shared__ float  zrow[EMBED];
  __shared__ double sv[256];
  __shared__ int    si[256];
  int n = *cnt; if (n > ZR) n = ZR;
  for (int e = blockIdx.x; e < n; e += gridDim.x) {
    int row = rows[e];
    __syncthreads();
    if (threadIdx.x < EMBED / 4)
      ((float4*)zrow)[threadIdx.x] = ((const float4*)(z + (size_t)row * EMBED))[threadIdx.x];
    __syncthreads();
    double bv = 1e300; int bi = VOCAB;
    for (int j = threadIdx.x; j < VOCAB; j += 256) {
      double d = 0.0;
      #pragma unroll
      for (int k = 0; k < EMBED; ++k) {
        double c = (double)cb[(size_t)j * EMBED + k];
        d += c * (c - 2.0 * (double)zrow[k]);
      }
      if (d < bv || (d == bv && j < bi)) { bv = d; bi = j; }
    }
    sv[threadIdx.x] = bv; si[threadIdx.x] = bi;
    __syncthreads();
    for (int s = 128; s > 0; s >>= 1) {
      if (threadIdx.x < (unsigned)s) {
        double ov = sv[threadIdx.x + s]; int oi = si[threadIdx.x + s];
        if (ov < sv[threadIdx.x] || (ov == sv[threadIdx.x] && oi < si[threadIdx.x])) {
          sv[threadIdx.x] = ov; si[threadIdx.x] = oi;
        }
      }
      __syncthreads();
    }
    if (threadIdx.x == 0) tokens[row] = si[0];
  }
}

// ---------- gather z_q: exact fp32 copy + bf16 copy for the decoder
__global__ __launch_bounds__(256) void gather_kernel(
    const int* __restrict__ tokens, const float* __restrict__ cb,
    float* __restrict__ zq, unsigned short* __restrict__ zqb)
{
  int g = blockIdx.x * 256 + threadIdx.x;            // (row, 16B-part)
  int row = g >> 4;
  int part = g & 15;
  int tok = tokens[row];
  float4 cv = ((const float4*)cb)[tok * 16 + part];
  ((float4*)zq)[g] = cv;
  ushort4 o;
  o.x = f2bf(cv.x); o.y = f2bf(cv.y); o.z = f2bf(cv.z); o.w = f2bf(cv.w);
  ((ushort4*)zqb)[g] = o;
}

extern "C" void kernel_launch(void* const* d_in, const int* in_sizes, int n_in,
                              void* d_out, int out_size, void* d_ws, size_t ws_size,
                              hipStream_t stream)
{
  const float* obs = (const float*)d_in[0];
  const float* ew1 = (const float*)d_in[1];
  const float* eb1 = (const float*)d_in[2];
  const float* ew2 = (const float*)d_in[3];
  const float* eb2 = (const float*)d_in[4];
  const float* dw1 = (const float*)d_in[5];
  const float* db1 = (const float*)d_in[6];
  const float* dw2 = (const float*)d_in[7];
  const float* db2 = (const float*)d_in[8];
  const float* cb  = (const float*)d_in[9];

  float* out_z   = (float*)d_out;                    // [65536][64]
  float* out_zq  = out_z + (size_t)ZR * EMBED;       // [65536][64]
  float* out_rec = out_z + 2 * (size_t)ZR * EMBED;   // [4096][128]

  // h 3-split (3 x 4MB) staged in the (dead-until-gather) out_zq slot
  unsigned short* h1 = (unsigned short*)out_zq;
  unsigned short* h2 = h1 + (size_t)BNR * HIDD;
  unsigned short* h3 = h2 + (size_t)BNR * HIDD;

  char* w = (char*)d_ws;
  _Float16* chi = (_Float16*)w;  w += (size_t)VOCAB * EMBED * 2;  // 512 KB
  _Float16* clo = (_Float16*)w;  w += (size_t)VOCAB * EMBED * 2;  // 512 KB
  float*    bcol = (float*)w;    w += 64 * 1024;                  // 16 KB used
  _Float16* zhi = (_Float16*)w;  w += (size_t)ZR * EMBED * 2;     // 8 MB
  _Float16* zlo = (_Float16*)w;  w += (size_t)ZR * EMBED * 2;     // 8 MB
  unsigned short* w1t1 = (unsigned short*)w; w += (size_t)HIDD * OBSD * 2;
  unsigned short* w1t2 = (unsigned short*)w; w += (size_t)HIDD * OBSD * 2;
  unsigned short* w1t3 = (unsigned short*)w; w += (size_t)HIDD * OBSD * 2;
  unsigned short* w2t1 = (unsigned short*)w; w += (size_t)ZD * HIDD * 2;
  unsigned short* w2t2 = (unsigned short*)w; w += (size_t)ZD * HIDD * 2;
  unsigned short* w2t3 = (unsigned short*)w; w += (size_t)ZD * HIDD * 2;
  unsigned short* d1t  = (unsigned short*)w; w += (size_t)HIDD * ZD * 2;
  unsigned short* d2t  = (unsigned short*)w; w += (size_t)OBSD * HIDD * 2;
  int* tokens = (int*)w;  w += (size_t)ZR * 4;
  int* rrows  = (int*)w;  w += (size_t)ZR * 4;
  int* rcnt   = (int*)w;  w += 64;
  float2* pb2 = (float2*)w; w += (size_t)NCHUNK * ZR * 8;         // 2 MB
  int*   pidx = (int*)w;    w += (size_t)NCHUNK * ZR * 4;         // 1 MB

  // overlays into zhi/zlo region (dead-time disjoint):
  // obs 3-split lives [prep..enc1]; zhi/zlo written by enc2 (after enc1)
  unsigned short* o1 = (unsigned short*)zhi;
  unsigned short* o2 = o1 + (size_t)BNR * OBSD;
  unsigned short* o3 = o2 + (size_t)BNR * OBSD;
  // zq bf16 lives [gather..dec1], zhi dead after dist
  unsigned short* zqb  = (unsigned short*)zhi;
  // dec hidden lives [dec1..dec2], zlo dead after dist
  unsigned short* hdec = (unsigned short*)zlo;

  prep_all_kernel<<<6672, 256, 0, stream>>>(
      cb, chi, clo, bcol,
      ew1, w1t1, w1t2, w1t3,
      ew2, w2t1, w2t2, w2t3,
      obs, o1, o2, o3,
      dw1, d1t, dw2, d2t, rcnt);

  // encoder (bf16 3-split MFMA + fp64 drain => np-fp32-grade z)
  enc_mfma_kernel<true><<<dim3(BNR / 64, HIDD / 64), 256, 0, stream>>>(
      o1, o2, o3, w1t1, w1t2, w1t3, eb1, BNR, HIDD, OBSD,
      h1, h2, h3, nullptr, nullptr, nullptr);
  enc_mfma_kernel<false><<<dim3(BNR / 64, ZD / 64), 256, 0, stream>>>(
      h1, h2, h3, w2t1, w2t2, w2t3, eb2, BNR, ZD, HIDD,
      nullptr, nullptr, nullptr, out_z, zhi, zlo);

  dist_kernel<<<dim3(ZR / 256, NCHUNK), 256, 0, stream>>>(
      zhi, zlo, chi, clo, bcol, pb2, pidx);
  merge_kernel<<<ZR / 256, 256, 0, stream>>>(pb2, pidx, tokens, rcnt, rrows);
  rescue_kernel<<<256, 256, 0, stream>>>(rcnt, rrows, out_z, cb, tokens);
  gather_kernel<<<(ZR * 16) / 256, 256, 0, stream>>>(tokens, cb, out_zq, zqb);

  // decoder (bf16 1-pass MFMA)
  dec_mfma_kernel<true, true><<<dim3(BNR / 64, HIDD / 64), 256, 0, stream>>>(
      zqb, d1t, db1, BNR, HIDD, ZD, hdec, nullptr);
  dec_mfma_kernel<false, false><<<dim3(BNR / 64, OBSD / 64), 256, 0, stream>>>(
      hdec, d2t, db2, BNR, OBSD, HIDD, nullptr, out_rec);
}

// Round 7
// 300.389 us; speedup vs baseline: 1.1240x; 1.1240x over previous
//
#include <hip/hip_runtime.h>
#include <math.h>

#define VOCAB 4096
#define EMBED 64
#define OBSD  128
#define HIDD  512
#define BNR   4096        // batch rows (1024*4)
#define ZR    65536       // token rows (BNR*16)
#define ZD    1024        // 16*EMBED
#define NCHUNK 4
#define CHSZ  (VOCAB / NCHUNK)   // 1024 codes per chunk
#define TCODES 64                // codes per LDS tile
#define NTILES (CHSZ / TCODES)   // 16 tiles per chunk

// scaled units: codebook scaled by 4096 in f16 space; margin covers worst-case
// f16-split + fp32-accum error (~5e-5) with 40x slack. Proven r1/r2/r4/r5/r6.
#define MARGIN_SCALED 2.0e-3f

// LDS layout strides (halfs), padded: slice stride 136 (not 128) to break
// power-of-2 bank alignment between k-slices.
#define SSTR 136
#define GSTR (8 * SSTR)          // 1088 halfs per 16-code group
#define TYPSZ (4 * GSTR)         // 4352 halfs per {hi|lo} per buffer

typedef _Float16 half8  __attribute__((ext_vector_type(8)));
typedef short    bf16x8 __attribute__((ext_vector_type(8)));
typedef float    f32x4  __attribute__((ext_vector_type(4)));

__device__ __forceinline__ f32x4 mfma_f16(half8 a, half8 b, f32x4 c){
  return __builtin_amdgcn_mfma_f32_16x16x32_f16(a,b,c,0,0,0);
}
__device__ __forceinline__ f32x4 mfma_bf(bf16x8 a, bf16x8 b, f32x4 c){
  return __builtin_amdgcn_mfma_f32_16x16x32_bf16(a,b,c,0,0,0);
}
__device__ __forceinline__ unsigned short f2bf(float f){
  union{float f; unsigned u;} x; x.f=f;
  unsigned u = x.u + 0x7fffu + ((x.u>>16)&1u);
  return (unsigned short)(u>>16);
}
__device__ __forceinline__ float bf2f(unsigned short h){
  union{unsigned u; float f;} x; x.u = ((unsigned)h)<<16; return x.f;
}
__device__ __forceinline__ void split3(float w, unsigned short& b1,
                                       unsigned short& b2, unsigned short& b3){
  b1 = f2bf(w); float r  = w - bf2f(b1);
  b2 = f2bf(r); float r2 = r - bf2f(b2);
  b3 = f2bf(r2);
}
__device__ __forceinline__ bf16x8 ldbf(const unsigned short* p){
  return *(const bf16x8*)(const void*)p;
}

// ---------- fused prep: cb f16-split + weight splits/transposes + rcnt zero
__global__ __launch_bounds__(256) void prep_all_kernel(
    const float* __restrict__ cb, _Float16* __restrict__ chi,
    _Float16* __restrict__ clo, float* __restrict__ bcol,
    const float* __restrict__ ew1, unsigned short* __restrict__ w1t1,
    unsigned short* __restrict__ w1t2, unsigned short* __restrict__ w1t3,
    const float* __restrict__ ew2, unsigned short* __restrict__ w2t1,
    unsigned short* __restrict__ w2t2, unsigned short* __restrict__ w2t3,
    const float* __restrict__ obs, unsigned short* __restrict__ o1,
    unsigned short* __restrict__ o2, unsigned short* __restrict__ o3,
    const float* __restrict__ dw1, unsigned short* __restrict__ d1t,
    const float* __restrict__ dw2, unsigned short* __restrict__ d2t,
    int* __restrict__ rcnt)
{
  const int b = blockIdx.x;
  const int t = threadIdx.x;
  if (b == 0 && t == 0) *rcnt = 0;
  if (b < 16) {
    // codebook: f16 hi/lo split (x4096 scale) + (-0.5*||c||^2)*4096
    int j = b * 256 + t;
    double s = 0.0;
    #pragma unroll 8
    for (int d = 0; d < EMBED; ++d) {
      float c = cb[j * EMBED + d];
      s += (double)c * (double)c;
      float cs = c * 4096.0f;             // exact (pow2 scale)
      _Float16 hi = (_Float16)cs;
      chi[j * EMBED + d] = hi;
      clo[j * EMBED + d] = (_Float16)(cs - (float)hi);
    }
    bcol[j] = (float)(-0.5 * s * 4096.0);
  } else if (b < 272) {
    // ew1 [OBSD][HIDD] -> 3-split [HIDD][OBSD]
    int e = (b - 16) * 256 + t;
    int n = e / OBSD, k = e % OBSD;
    split3(ew1[(size_t)k * HIDD + n], w1t1[e], w1t2[e], w1t3[e]);
  } else if (b < 2320) {
    // ew2 [HIDD][ZD] -> 3-split [ZD][HIDD]
    int e = (b - 272) * 256 + t;
    int n = e / HIDD, k = e % HIDD;
    split3(ew2[(size_t)k * ZD + n], w2t1[e], w2t2[e], w2t3[e]);
  } else if (b < 4368) {
    // obs elementwise 3-split
    int e = (b - 2320) * 256 + t;
    split3(obs[e], o1[e], o2[e], o3[e]);
  } else if (b < 6416) {
    // dw1 [ZD][HIDD] -> bf16 [HIDD][ZD]
    int e = (b - 4368) * 256 + t;
    int n = e / ZD, k = e % ZD;
    d1t[e] = f2bf(dw1[(size_t)k * HIDD + n]);
  } else {
    // dw2 [HIDD][OBSD] -> bf16 [OBSD][HIDD]
    int e = (b - 6416) * 256 + t;
    int n = e / HIDD, k = e % HIDD;
    d2t[e] = f2bf(dw2[(size_t)k * OBSD + n]);
  }
}

// ---------- encoder GEMM: bf16 3-split, 6 MFMA passes, per-k-step fp64 drain.
template<bool RELU>
__global__ __launch_bounds__(256) void enc_mfma_kernel(
    const unsigned short* __restrict__ A1, const unsigned short* __restrict__ A2,
    const unsigned short* __restrict__ A3,
    const unsigned short* __restrict__ B1, const unsigned short* __restrict__ B2,
    const unsigned short* __restrict__ B3,
    const float* __restrict__ bias, int M, int N, int K,
    unsigned short* __restrict__ H1, unsigned short* __restrict__ H2,
    unsigned short* __restrict__ H3,
    float* __restrict__ Z, _Float16* __restrict__ Zhi, _Float16* __restrict__ Zlo)
{
  const int tid  = threadIdx.x;
  const int wave = tid >> 6;
  const int lane = tid & 63;
  const int l15  = lane & 15;
  const int lg   = lane >> 4;
  const int m0 = blockIdx.x * 64 + (wave >> 1) * 32;
  const int n0 = blockIdx.y * 64 + (wave & 1) * 32;

  double accd[2][2][4] = {};

  for (int k0 = 0; k0 < K; k0 += 32) {
    bf16x8 a1[2], a2[2], a3[2], b1[2], b2[2], b3[2];
    #pragma unroll
    for (int ms = 0; ms < 2; ++ms) {
      size_t base = (size_t)(m0 + ms * 16 + l15) * K + k0 + lg * 8;
      a1[ms] = ldbf(A1 + base); a2[ms] = ldbf(A2 + base); a3[ms] = ldbf(A3 + base);
    }
    #pragma unroll
    for (int ns = 0; ns < 2; ++ns) {
      size_t base = (size_t)(n0 + ns * 16 + l15) * K + k0 + lg * 8;
      b1[ns] = ldbf(B1 + base); b2[ns] = ldbf(B2 + base); b3[ns] = ldbf(B3 + base);
    }
    #pragma unroll
    for (int ms = 0; ms < 2; ++ms)
      #pragma unroll
      for (int ns = 0; ns < 2; ++ns) {
        f32x4 acc = {0.f, 0.f, 0.f, 0.f};
        // smallest terms first, dominant a1*b1 last
        acc = mfma_bf(a1[ms], b3[ns], acc);
        acc = mfma_bf(a2[ms], b2[ns], acc);
        acc = mfma_bf(a3[ms], b1[ns], acc);
        acc = mfma_bf(a1[ms], b2[ns], acc);
        acc = mfma_bf(a2[ms], b1[ns], acc);
        acc = mfma_bf(a1[ms], b1[ns], acc);
        #pragma unroll
        for (int r = 0; r < 4; ++r) accd[ms][ns][r] += (double)acc[r];
      }
  }

  #pragma unroll
  for (int ms = 0; ms < 2; ++ms)
    #pragma unroll
    for (int ns = 0; ns < 2; ++ns)
      #pragma unroll
      for (int r = 0; r < 4; ++r) {
        int row = m0 + ms * 16 + lg * 4 + r;
        int col = n0 + ns * 16 + l15;
        float v = (float)accd[ms][ns][r] + bias[col];
        size_t o = (size_t)row * N + col;
        if constexpr (RELU) {
          v = v > 0.f ? v : 0.f;
          split3(v, H1[o], H2[o], H3[o]);
        } else {
          Z[o] = v;
          _Float16 hi = (_Float16)v;
          Zhi[o] = hi;
          Zlo[o] = (_Float16)(v - (float)hi);
        }
      }
}

// ---------- decoder GEMM: plain bf16 1-pass MFMA (2%-of-max tolerance)
template<bool RELU, bool OUTBF>
__global__ __launch_bounds__(256) void dec_mfma_kernel(
    const unsigned short* __restrict__ A, const unsigned short* __restrict__ B,
    const float* __restrict__ bias, int M, int N, int K,
    unsigned short* __restrict__ Obf, float* __restrict__ Of)
{
  const int tid  = threadIdx.x;
  const int wave = tid >> 6;
  const int lane = tid & 63;
  const int l15  = lane & 15;
  const int lg   = lane >> 4;
  const int m0 = blockIdx.x * 64 + (wave >> 1) * 32;
  const int n0 = blockIdx.y * 64 + (wave & 1) * 32;

  f32x4 acc[2][2] = {};
  for (int k0 = 0; k0 < K; k0 += 32) {
    bf16x8 a[2], b[2];
    #pragma unroll
    for (int ms = 0; ms < 2; ++ms)
      a[ms] = ldbf(A + (size_t)(m0 + ms * 16 + l15) * K + k0 + lg * 8);
    #pragma unroll
    for (int ns = 0; ns < 2; ++ns)
      b[ns] = ldbf(B + (size_t)(n0 + ns * 16 + l15) * K + k0 + lg * 8);
    #pragma unroll
    for (int ms = 0; ms < 2; ++ms)
      #pragma unroll
      for (int ns = 0; ns < 2; ++ns)
        acc[ms][ns] = mfma_bf(a[ms], b[ns], acc[ms][ns]);
  }
  #pragma unroll
  for (int ms = 0; ms < 2; ++ms)
    #pragma unroll
    for (int ns = 0; ns < 2; ++ns)
      #pragma unroll
      for (int r = 0; r < 4; ++r) {
        int row = m0 + ms * 16 + lg * 4 + r;
        int col = n0 + ns * 16 + l15;
        float v = acc[ms][ns][r] + bias[col];
        if constexpr (RELU) v = v > 0.f ? v : 0.f;
        if constexpr (OUTBF) Obf[(size_t)row * N + col] = f2bf(v);
        else                 Of[(size_t)row * N + col] = v;
      }
}

// ---------- VQ distance: chunked, LDS-staged codebook, 16 waves/block.
// r5/r6 evidence: only ~1 LDS-bearing block is resident per CU regardless of
// nominal limits, so waves-per-block IS waves-per-CU. 1024 thr = 16 waves
// (4/SIMD) overlap MFMA, VALU argmin and ds_read/barrier latency. Each wave
// owns 32 rows (2 subtiles); single 6-MFMA chain per (s,grp), bcol-seeded.
// NOTE: no min-waves clause — a VGPR cap makes the compiler demote the
// loop-invariant z fragments to per-iteration reloads (r3: 2 GB HBM, 3x slower).
__global__ __launch_bounds__(1024) void dist_kernel(
    const _Float16* __restrict__ zhi, const _Float16* __restrict__ zlo,
    const _Float16* __restrict__ chi, const _Float16* __restrict__ clo,
    const float* __restrict__ bcol,
    float2* __restrict__ pb2, int* __restrict__ pidx)
{
  __shared__ _Float16 sh[2][2][TYPSZ];   // [buf][hi|lo][padded tile]
  __shared__ float    sbc[CHSZ];

  const int tid  = threadIdx.x;
  const int wave = tid >> 6;
  const int lane = tid & 63;
  const int l15  = lane & 15;
  const int lg   = lane >> 4;
  const int rowW = blockIdx.x * 512 + wave * 32;
  const int ch   = blockIdx.y;

  // z fragments: loop-invariant, stay in VGPRs (2 subtiles x 4 frags x 4 regs)
  half8 ah0[2], ah1[2], al0[2], al1[2];
  #pragma unroll
  for (int s = 0; s < 2; ++s) {
    const size_t base = (size_t)(rowW + s * 16 + l15) * EMBED + lg * 8;
    ah0[s] = *(const half8*)(zhi + base);
    ah1[s] = *(const half8*)(zhi + base + 32);
    al0[s] = *(const half8*)(zlo + base);
    al1[s] = *(const half8*)(zlo + base + 32);
  }

  // staging: 1024 16B-chunks per tile (512 hi + 512 lo); thread t handles
  // exactly one chunk — perfectly coalesced global read, one LDS write.
  const int typ = tid >> 9;                  // 0 chi, 1 clo
  const int cc  = tid & 511;                 // chunk within type
  const _Float16* gsrc = (typ ? clo : chi) + (size_t)ch * CHSZ * EMBED;
  const int code = cc >> 3, sl = cc & 7;
  const int ld = (code >> 4) * GSTR + sl * SSTR + (code & 15) * 8;

  // bcol for this chunk -> LDS
  for (int i = tid; i < CHSZ; i += 1024) sbc[i] = bcol[ch * CHSZ + i];

  // prologue: stage tile 0 into buf 0
  *(half8*)(&sh[0][typ][ld]) = *(const half8*)(gsrc + (size_t)cc * 8);
  __syncthreads();

  float best[2][4], second[2][4];
  int   bidx[2][4];
  #pragma unroll
  for (int s = 0; s < 2; ++s)
    #pragma unroll
    for (int r = 0; r < 4; ++r) {
      best[s][r] = -INFINITY; second[s][r] = -INFINITY; bidx[s][r] = 0;
    }

  for (int tile = 0; tile < NTILES; ++tile) {
    const int buf = tile & 1;
    // issue next tile's global load early; written to LDS after the barrier
    half8 v0 = {};
    if (tile + 1 < NTILES)
      v0 = *(const half8*)(gsrc + (size_t)(tile + 1) * 4096 + (size_t)cc * 8);

    const _Float16* ph = &sh[buf][0][0];
    const _Float16* pl = &sh[buf][1][0];
    #pragma unroll
    for (int grp = 0; grp < 4; ++grp) {
      const int rb = grp * GSTR + l15 * 8;
      half8 bh0 = *(const half8*)(ph + rb + lg * SSTR);
      half8 bh1 = *(const half8*)(ph + rb + (4 + lg) * SSTR);
      half8 bl0 = *(const half8*)(pl + rb + lg * SSTR);
      half8 bl1 = *(const half8*)(pl + rb + (4 + lg) * SSTR);
      const int cloc = tile * TCODES + grp * 16 + l15;
      const int col  = ch * CHSZ + cloc;
      const float vb = sbc[cloc];
      const f32x4 seed = {vb, vb, vb, vb};     // shared across the 2 s-chains
      #pragma unroll
      for (int s = 0; s < 2; ++s) {
        // single chain, smallest terms first, dominant hi*hi last
        f32x4 acc = seed;
        acc = mfma_f16(ah0[s], bl0, acc);
        acc = mfma_f16(ah1[s], bl1, acc);
        acc = mfma_f16(al0[s], bh0, acc);
        acc = mfma_f16(al1[s], bh1, acc);
        acc = mfma_f16(ah0[s], bh0, acc);
        acc = mfma_f16(ah1[s], bh1, acc);
        #pragma unroll
        for (int r = 0; r < 4; ++r) {
          float v = acc[r];
          float sn = __builtin_amdgcn_fmed3f(second[s][r], best[s][r], v);
          bool gt = v > best[s][r];
          best[s][r] = gt ? v : best[s][r];
          bidx[s][r] = gt ? col : bidx[s][r];
          second[s][r] = sn;
        }
      }
    }
    __syncthreads();              // all waves done reading buf^1 (last iter)
    if (tile + 1 < NTILES)
      *(half8*)(&sh[buf ^ 1][typ][ld]) = v0;
    __syncthreads();              // next tile visible
  }

  // reduce (best,second,idx) across the 16 col-lanes (low 4 lane bits)
  #pragma unroll
  for (int m = 1; m <= 8; m <<= 1) {
    #pragma unroll
    for (int s = 0; s < 2; ++s)
      #pragma unroll
      for (int r = 0; r < 4; ++r) {
        float ob = __shfl_xor(best[s][r], m, 64);
        float os = __shfl_xor(second[s][r], m, 64);
        int   oi = __shfl_xor(bidx[s][r], m, 64);
        float mn = fminf(best[s][r], ob);
        second[s][r] = fmaxf(mn, fmaxf(second[s][r], os));
        if (ob > best[s][r]) { best[s][r] = ob; bidx[s][r] = oi; }
      }
  }

  if (l15 == 0) {
    #pragma unroll
    for (int s = 0; s < 2; ++s)
      #pragma unroll
      for (int r = 0; r < 4; ++r) {
        int row = rowW + s * 16 + lg * 4 + r;
        pb2 [(size_t)ch * ZR + row] = make_float2(best[s][r], second[s][r]);
        pidx[(size_t)ch * ZR + row] = bidx[s][r];
      }
  }
}

// ---------- merge chunk partials -> tokens + rescue list
__global__ __launch_bounds__(256) void merge_kernel(
    const float2* __restrict__ pb2, const int* __restrict__ pidx,
    int* __restrict__ tokens, int* __restrict__ rcnt, int* __restrict__ rrows)
{
  int r = blockIdx.x * 256 + threadIdx.x;
  float b = -INFINITY, s = -INFINITY;
  int bi = 0;
  #pragma unroll
  for (int c = 0; c < NCHUNK; ++c) {
    float2 p = pb2[(size_t)c * ZR + r];
    int    i = pidx[(size_t)c * ZR + r];
    if (p.x > b) { s = fmaxf(b, p.y); b = p.x; bi = i; }
    else         { s = fmaxf(s, p.x); }
  }
  tokens[r] = bi;
  if (b - s < MARGIN_SCALED) {
    int p = atomicAdd(rcnt, 1);
    if (p < ZR) rrows[p] = r;
  }
}

// ---------- exact fp64 rescan for ambiguous tokens (correctness anchor)
__global__ __launch_bounds__(256) void rescue_kernel(
    const int* __restrict__ cnt, const int* __restrict__ rows,
    const float* __restrict__ z, const float* __restrict__ cb,
    int* __restrict__ tokens)
{
  __shared__ float  zrow[EMBED];
  __shared__ double sv[256];
  __shared__ int    si[256];
  int n = *cnt; if (n > ZR) n = ZR;
  for (int e = blockIdx.x; e < n; e += gridDim.x) {
    int row = rows[e];
    __syncthreads();
    if (threadIdx.x < EMBED / 4)
      ((float4*)zrow)[threadIdx.x] = ((const float4*)(z + (size_t)row * EMBED))[threadIdx.x];
    __syncthreads();
    double bv = 1e300; int bi = VOCAB;
    for (int j = threadIdx.x; j < VOCAB; j += 256) {
      double d = 0.0;
      #pragma unroll
      for (int k = 0; k < EMBED; ++k) {
        double c = (double)cb[(size_t)j * EMBED + k];
        d += c * (c - 2.0 * (double)zrow[k]);
      }
      if (d < bv || (d == bv && j < bi)) { bv = d; bi = j; }
    }
    sv[threadIdx.x] = bv; si[threadIdx.x] = bi;
    __syncthreads();
    for (int s = 128; s > 0; s >>= 1) {
      if (threadIdx.x < (unsigned)s) {
        double ov = sv[threadIdx.x + s]; int oi = si[threadIdx.x + s];
        if (ov < sv[threadIdx.x] || (ov == sv[threadIdx.x] && oi < si[threadIdx.x])) {
          sv[threadIdx.x] = ov; si[threadIdx.x] = oi;
        }
      }
      __syncthreads();
    }
    if (threadIdx.x == 0) tokens[row] = si[0];
  }
}

// ---------- gather z_q: exact fp32 copy + bf16 copy for the decoder
__global__ __launch_bounds__(256) void gather_kernel(
    const int* __restrict__ tokens, const float* __restrict__ cb,
    float* __restrict__ zq, unsigned short* __restrict__ zqb)
{
  int g = blockIdx.x * 256 + threadIdx.x;            // (row, 16B-part)
  int row = g >> 4;
  int part = g & 15;
  int tok = tokens[row];
  float4 cv = ((const float4*)cb)[tok * 16 + part];
  ((float4*)zq)[g] = cv;
  ushort4 o;
  o.x = f2bf(cv.x); o.y = f2bf(cv.y); o.z = f2bf(cv.z); o.w = f2bf(cv.w);
  ((ushort4*)zqb)[g] = o;
}

extern "C" void kernel_launch(void* const* d_in, const int* in_sizes, int n_in,
                              void* d_out, int out_size, void* d_ws, size_t ws_size,
                              hipStream_t stream)
{
  const float* obs = (const float*)d_in[0];
  const float* ew1 = (const float*)d_in[1];
  const float* eb1 = (const float*)d_in[2];
  const float* ew2 = (const float*)d_in[3];
  const float* eb2 = (const float*)d_in[4];
  const float* dw1 = (const float*)d_in[5];
  const float* db1 = (const float*)d_in[6];
  const float* dw2 = (const float*)d_in[7];
  const float* db2 = (const float*)d_in[8];
  const float* cb  = (const float*)d_in[9];

  float* out_z   = (float*)d_out;                    // [65536][64]
  float* out_zq  = out_z + (size_t)ZR * EMBED;       // [65536][64]
  float* out_rec = out_z + 2 * (size_t)ZR * EMBED;   // [4096][128]

  // h 3-split (3 x 4MB) staged in the (dead-until-gather) out_zq slot
  unsigned short* h1 = (unsigned short*)out_zq;
  unsigned short* h2 = h1 + (size_t)BNR * HIDD;
  unsigned short* h3 = h2 + (size_t)BNR * HIDD;

  char* w = (char*)d_ws;
  _Float16* chi = (_Float16*)w;  w += (size_t)VOCAB * EMBED * 2;  // 512 KB
  _Float16* clo = (_Float16*)w;  w += (size_t)VOCAB * EMBED * 2;  // 512 KB
  float*    bcol = (float*)w;    w += 64 * 1024;                  // 16 KB used
  _Float16* zhi = (_Float16*)w;  w += (size_t)ZR * EMBED * 2;     // 8 MB
  _Float16* zlo = (_Float16*)w;  w += (size_t)ZR * EMBED * 2;     // 8 MB
  unsigned short* w1t1 = (unsigned short*)w; w += (size_t)HIDD * OBSD * 2;
  unsigned short* w1t2 = (unsigned short*)w; w += (size_t)HIDD * OBSD * 2;
  unsigned short* w1t3 = (unsigned short*)w; w += (size_t)HIDD * OBSD * 2;
  unsigned short* w2t1 = (unsigned short*)w; w += (size_t)ZD * HIDD * 2;
  unsigned short* w2t2 = (unsigned short*)w; w += (size_t)ZD * HIDD * 2;
  unsigned short* w2t3 = (unsigned short*)w; w += (size_t)ZD * HIDD * 2;
  unsigned short* d1t  = (unsigned short*)w; w += (size_t)HIDD * ZD * 2;
  unsigned short* d2t  = (unsigned short*)w; w += (size_t)OBSD * HIDD * 2;
  int* tokens = (int*)w;  w += (size_t)ZR * 4;
  int* rrows  = (int*)w;  w += (size_t)ZR * 4;
  int* rcnt   = (int*)w;  w += 64;
  float2* pb2 = (float2*)w; w += (size_t)NCHUNK * ZR * 8;         // 2 MB
  int*   pidx = (int*)w;    w += (size_t)NCHUNK * ZR * 4;         // 1 MB

  // overlays into zhi/zlo region (dead-time disjoint):
  // obs 3-split lives [prep..enc1]; zhi/zlo written by enc2 (after enc1)
  unsigned short* o1 = (unsigned short*)zhi;
  unsigned short* o2 = o1 + (size_t)BNR * OBSD;
  unsigned short* o3 = o2 + (size_t)BNR * OBSD;
  // zq bf16 lives [gather..dec1], zhi dead after dist
  unsigned short* zqb  = (unsigned short*)zhi;
  // dec hidden lives [dec1..dec2], zlo dead after dist
  unsigned short* hdec = (unsigned short*)zlo;

  prep_all_kernel<<<6672, 256, 0, stream>>>(
      cb, chi, clo, bcol,
      ew1, w1t1, w1t2, w1t3,
      ew2, w2t1, w2t2, w2t3,
      obs, o1, o2, o3,
      dw1, d1t, dw2, d2t, rcnt);

  // encoder (bf16 3-split MFMA + fp64 drain => np-fp32-grade z)
  enc_mfma_kernel<true><<<dim3(BNR / 64, HIDD / 64), 256, 0, stream>>>(
      o1, o2, o3, w1t1, w1t2, w1t3, eb1, BNR, HIDD, OBSD,
      h1, h2, h3, nullptr, nullptr, nullptr);
  enc_mfma_kernel<false><<<dim3(BNR / 64, ZD / 64), 256, 0, stream>>>(
      h1, h2, h3, w2t1, w2t2, w2t3, eb2, BNR, ZD, HIDD,
      nullptr, nullptr, nullptr, out_z, zhi, zlo);

  dist_kernel<<<dim3(ZR / 512, NCHUNK), 1024, 0, stream>>>(
      zhi, zlo, chi, clo, bcol, pb2, pidx);
  merge_kernel<<<ZR / 256, 256, 0, stream>>>(pb2, pidx, tokens, rcnt, rrows);
  rescue_kernel<<<256, 256, 0, stream>>>(rcnt, rrows, out_z, cb, tokens);
  gather_kernel<<<(ZR * 16) / 256, 256, 0, stream>>>(tokens, cb, out_zq, zqb);

  // decoder (bf16 1-pass MFMA)
  dec_mfma_kernel<true, true><<<dim3(BNR / 64, HIDD / 64), 256, 0, stream>>>(
      zqb, d1t, db1, BNR, HIDD, ZD, hdec, nullptr);
  dec_mfma_kernel<false, false><<<dim3(BNR / 64, OBSD / 64), 256, 0, stream>>>(
      hdec, d2t, db2, BNR, OBSD, HIDD, nullptr, out_rec);
}